// Round 1
// baseline (482.016 us; speedup 1.0000x reference)
//
#include <hip/hip_runtime.h>

#define B 4
#define M 8192
#define NSTY 8192
#define KNB 8
#define F 288
#define NT (M + NSTY)

// ---------------- degree histogram ----------------
__global__ void deg_kernel(const int* __restrict__ idx_k1, const int* __restrict__ idx_k2,
                           int* __restrict__ deg) {
    int t = blockIdx.x * blockDim.x + threadIdx.x;
    if (t >= B * M * KNB) return;
    int b = t / (M * KNB);
    atomicAdd(&deg[b * NT + idx_k2[t]], 1);          // content sources
    atomicAdd(&deg[b * NT + M + idx_k1[t]], 1);      // style sources
}

__global__ void rsqrt_kernel(float* __restrict__ dsc) {
    int t = blockIdx.x * blockDim.x + threadIdx.x;
    if (t >= B * NT) return;
    int d = ((const int*)dsc)[t];
    dsc[t] = rsqrtf((float)(d < 1 ? 1 : d));
}

// ---------------- layer-1 gather: agg1[b,v,:] = 0.25 * sum_16 feat[u]*w_u ----------------
__global__ void agg1_kernel(const float* __restrict__ feat_c, const float* __restrict__ feat_s,
                            const int* __restrict__ idx_k1, const int* __restrict__ idx_k2,
                            const float* __restrict__ dsc, float* __restrict__ agg) {
    int bv = blockIdx.x;            // b*M + v
    int b  = bv >> 13;
    __shared__ int   nb[16];
    __shared__ float wt[16];
    int tid = threadIdx.x;
    if (tid < 8) {
        int u = idx_k2[(size_t)bv * KNB + tid];
        nb[tid] = u;
        wt[tid] = dsc[b * NT + u];
    } else if (tid < 16) {
        int u = idx_k1[(size_t)bv * KNB + (tid - 8)] + M;
        nb[tid] = u;
        wt[tid] = dsc[b * NT + u];
    }
    __syncthreads();
    for (int f = tid; f < F; f += 128) {
        float acc = 0.f;
        #pragma unroll
        for (int k = 0; k < 16; ++k) {
            int u = nb[k];   // uniform across block -> no divergence
            const float* src = (u < M) ? (feat_c + ((size_t)b * M + u) * F)
                                       : (feat_s + ((size_t)b * NSTY + (u - M)) * F);
            acc += src[f] * wt[k];
        }
        agg[(size_t)bv * F + f] = acc * 0.25f;
    }
}

// ---------------- layer-2 gather: 8 content neighbors of h1 + style constant term ----------------
__global__ void agg2_kernel(const float* __restrict__ h1,      // [B*M, F] (lives in d_out)
                            const int* __restrict__ idx_k1, const int* __restrict__ idx_k2,
                            const float* __restrict__ dsc, const float* __restrict__ b1,
                            float* __restrict__ agg) {
    int bv = blockIdx.x;
    int b  = bv >> 13;
    __shared__ int   nb[8];
    __shared__ float wt[8];
    __shared__ float sw[8];
    int tid = threadIdx.x;
    if (tid < 8) {
        int u = idx_k2[(size_t)bv * KNB + tid];
        nb[tid] = u;
        wt[tid] = dsc[b * NT + u];
    } else if (tid < 16) {
        int u = idx_k1[(size_t)bv * KNB + (tid - 8)] + M;
        sw[tid - 8] = dsc[b * NT + u];
    }
    __syncthreads();
    float S = sw[0]+sw[1]+sw[2]+sw[3]+sw[4]+sw[5]+sw[6]+sw[7];
    for (int f = tid; f < F; f += 128) {
        float acc = fmaxf(b1[f], 0.f) * S;   // h1[style] = relu(b1), scaled per-edge
        #pragma unroll
        for (int k = 0; k < 8; ++k)
            acc += h1[((size_t)b * M + nb[k]) * F + f] * wt[k];
        agg[(size_t)bv * F + f] = acc * 0.25f;
    }
}

// ---------------- fp32 tiled GEMM: C[32768,288] = A @ W + bias (opt. relu) ----------------
template<bool RELU>
__global__ void gemm_kernel(const float* __restrict__ A, const float* __restrict__ W,
                            const float* __restrict__ bias, float* __restrict__ C) {
    __shared__ float sA[64][17];   // [row][kk]
    __shared__ float sB[16][65];   // [kk][col]
    int tid = threadIdx.x;
    int tx = tid & 15, ty = tid >> 4;
    int row0 = blockIdx.y * 64;
    int col0 = blockIdx.x * 64;
    float acc[4][4] = {};

    for (int k0 = 0; k0 < F; k0 += 16) {
        // A tile 64x16 (rows always valid: 32768 % 64 == 0; K=288 % 16 == 0)
        {
            int e = tid * 4;
            int r = e >> 4, kk = e & 15;
            const float4 a4 = *(const float4*)(A + (size_t)(row0 + r) * F + k0 + kk);
            sA[r][kk+0] = a4.x; sA[r][kk+1] = a4.y; sA[r][kk+2] = a4.z; sA[r][kk+3] = a4.w;
        }
        // W tile 16x64 (col guard: float4-granular, 288 % 4 == 0 -> all-or-nothing)
        {
            int e = tid * 4;
            int kk = e >> 6, c = e & 63;
            int gc = col0 + c;
            float4 w4 = {0.f, 0.f, 0.f, 0.f};
            if (gc < F) w4 = *(const float4*)(W + (size_t)(k0 + kk) * F + gc);
            sB[kk][c+0] = w4.x; sB[kk][c+1] = w4.y; sB[kk][c+2] = w4.z; sB[kk][c+3] = w4.w;
        }
        __syncthreads();
        #pragma unroll
        for (int kk = 0; kk < 16; ++kk) {
            float a[4], bb[4];
            #pragma unroll
            for (int i = 0; i < 4; ++i) a[i] = sA[ty*4+i][kk];
            #pragma unroll
            for (int j = 0; j < 4; ++j) bb[j] = sB[kk][tx*4+j];
            #pragma unroll
            for (int i = 0; i < 4; ++i)
                #pragma unroll
                for (int j = 0; j < 4; ++j)
                    acc[i][j] += a[i] * bb[j];
        }
        __syncthreads();
    }

    int cbase = col0 + tx * 4;
    if (cbase < F) {
        float4 bv = *(const float4*)(bias + cbase);
        #pragma unroll
        for (int i = 0; i < 4; ++i) {
            int r = row0 + ty * 4 + i;
            float4 o;
            o.x = acc[i][0] + bv.x; o.y = acc[i][1] + bv.y;
            o.z = acc[i][2] + bv.z; o.w = acc[i][3] + bv.w;
            if (RELU) {
                o.x = fmaxf(o.x, 0.f); o.y = fmaxf(o.y, 0.f);
                o.z = fmaxf(o.z, 0.f); o.w = fmaxf(o.w, 0.f);
            }
            *(float4*)(C + (size_t)r * F + cbase) = o;
        }
    }
}

extern "C" void kernel_launch(void* const* d_in, const int* in_sizes, int n_in,
                              void* d_out, int out_size, void* d_ws, size_t ws_size,
                              hipStream_t stream) {
    const float* feat_c = (const float*)d_in[0];
    const float* feat_s = (const float*)d_in[1];
    const int*   idx_k1 = (const int*)d_in[2];
    const int*   idx_k2 = (const int*)d_in[3];
    const float* W1     = (const float*)d_in[4];
    const float* b1     = (const float*)d_in[5];
    const float* W2     = (const float*)d_in[6];
    const float* b2     = (const float*)d_in[7];
    float* out = (float*)d_out;

    char* ws = (char*)d_ws;
    float* dsc = (float*)ws;                                           // B*NT floats
    float* agg = (float*)(ws + (((size_t)B * NT * 4 + 255) / 256) * 256); // B*M*F floats

    hipMemsetAsync(dsc, 0, (size_t)B * NT * sizeof(int), stream);
    deg_kernel<<<(B * M * KNB + 255) / 256, 256, 0, stream>>>(idx_k1, idx_k2, (int*)dsc);
    rsqrt_kernel<<<(B * NT + 255) / 256, 256, 0, stream>>>(dsc);

    // layer 1: aggregate -> agg (ws), GEMM+bias+relu -> h1 (stored in d_out)
    agg1_kernel<<<B * M, 128, 0, stream>>>(feat_c, feat_s, idx_k1, idx_k2, dsc, agg);
    gemm_kernel<true><<<dim3(5, 512), 256, 0, stream>>>(agg, W1, b1, out);

    // layer 2: aggregate from h1 (d_out) -> agg (ws), GEMM+bias -> d_out
    agg2_kernel<<<B * M, 128, 0, stream>>>(out, idx_k1, idx_k2, dsc, b1, agg);
    gemm_kernel<false><<<dim3(5, 512), 256, 0, stream>>>(agg, W2, b2, out);
}

// Round 2
// 264.483 us; speedup vs baseline: 1.8225x; 1.8225x over previous
//
#include <hip/hip_runtime.h>

#define B 4
#define M 8192
#define NSTY 8192
#define KNB 8
#define F 288
#define NT (M + NSTY)   // 16384
#define BM (B * M)      // 32768

typedef __attribute__((ext_vector_type(8))) short short8;
typedef __attribute__((ext_vector_type(4))) float floatx4;

__device__ __forceinline__ float b2f(unsigned short h) {
    union { unsigned int u; float f; } c; c.u = ((unsigned int)h) << 16; return c.f;
}
__device__ __forceinline__ unsigned short f2b(float x) {
    union { float f; unsigned int u; } c; c.f = x;
    unsigned int r = c.u + 0x7FFFu + ((c.u >> 16) & 1u);
    return (unsigned short)(r >> 16);
}
__device__ __forceinline__ void gload_lds16(const void* g, void* l) {
    __builtin_amdgcn_global_load_lds(
        (const __attribute__((address_space(1))) unsigned int*)g,
        (__attribute__((address_space(3))) unsigned int*)l, 16, 0, 0);
}

// ---------------- degree histogram + rsqrt ----------------
__global__ void deg_kernel(const int* __restrict__ idx_k1, const int* __restrict__ idx_k2,
                           int* __restrict__ deg) {
    int t = blockIdx.x * blockDim.x + threadIdx.x;
    if (t >= B * M * KNB) return;
    int b = t / (M * KNB);
    atomicAdd(&deg[b * NT + idx_k2[t]], 1);
    atomicAdd(&deg[b * NT + M + idx_k1[t]], 1);
}

__global__ void rsqrt_kernel(float* __restrict__ dsc) {
    int t = blockIdx.x * blockDim.x + threadIdx.x;
    if (t >= B * NT) return;
    int d = ((const int*)dsc)[t];
    dsc[t] = rsqrtf((float)(d < 1 ? 1 : d));
}

// ---------------- pack W [F][F] fp32 -> Wp [F/8][F][8] bf16 ----------------
__global__ void packw_kernel(const float* __restrict__ W, unsigned short* __restrict__ Wp) {
    int t = blockIdx.x * 256 + threadIdx.x;
    if (t >= F * F) return;
    int k = t / F, n = t - k * F;
    Wp[((size_t)(k >> 3) * F + n) * 8 + (k & 7)] = f2b(W[t]);
}

// ---------------- convert feat_c|feat_s fp32 -> featb [B][NT][F] bf16 ----------------
__global__ void convert_kernel(const float* __restrict__ fc, const float* __restrict__ fs,
                               unsigned short* __restrict__ fb) {
    unsigned int t = blockIdx.x * 256 + threadIdx.x;
    unsigned int e = t * 4;
    if (e >= (unsigned int)(B) * NT * F) return;
    int row = (int)(e / F);
    int f = (int)(e - (unsigned int)row * F);
    int b = row >> 14, v = row & (NT - 1);
    const float* src = (v < M) ? fc + ((size_t)b * M + v) * F + f
                               : fs + ((size_t)b * NSTY + (v - M)) * F + f;
    float4 x = *(const float4*)src;
    uint2 o;
    o.x = (unsigned int)f2b(x.x) | ((unsigned int)f2b(x.y) << 16);
    o.y = (unsigned int)f2b(x.z) | ((unsigned int)f2b(x.w) << 16);
    *(uint2*)(fb + e) = o;
}

// ---------------- layer-1 gather (one wave per dst row) ----------------
__global__ void agg1_kernel(const unsigned short* __restrict__ fb,
                            const int* __restrict__ idx_k1, const int* __restrict__ idx_k2,
                            const float* __restrict__ dsc, unsigned short* __restrict__ aggb) {
    int wid = threadIdx.x >> 6, lane = threadIdx.x & 63;
    int bv = blockIdx.x * 4 + wid;
    int b = bv >> 13;
    int u = 0; float w = 0.f;
    if (lane < 8)       { u = idx_k2[(size_t)bv * KNB + lane]; w = dsc[b * NT + u]; }
    else if (lane < 16) { u = M + idx_k1[(size_t)bv * KNB + (lane - 8)]; w = dsc[b * NT + u]; }
    float a0[4] = {0.f, 0.f, 0.f, 0.f};
    float a1[4] = {0.f, 0.f, 0.f, 0.f};
    const unsigned short* base = fb + (size_t)b * NT * F;
    #pragma unroll
    for (int k = 0; k < 16; ++k) {
        int   uk = __shfl(u, k);
        float wk = __shfl(w, k);
        const unsigned short* src = base + (size_t)uk * F;
        uint2 d0 = *(const uint2*)(src + 4 * lane);
        a0[0] += wk * b2f((unsigned short)(d0.x & 0xFFFF));
        a0[1] += wk * b2f((unsigned short)(d0.x >> 16));
        a0[2] += wk * b2f((unsigned short)(d0.y & 0xFFFF));
        a0[3] += wk * b2f((unsigned short)(d0.y >> 16));
        if (lane < 8) {
            uint2 d1 = *(const uint2*)(src + 256 + 4 * lane);
            a1[0] += wk * b2f((unsigned short)(d1.x & 0xFFFF));
            a1[1] += wk * b2f((unsigned short)(d1.x >> 16));
            a1[2] += wk * b2f((unsigned short)(d1.y & 0xFFFF));
            a1[3] += wk * b2f((unsigned short)(d1.y >> 16));
        }
    }
    unsigned short* dst = aggb + (size_t)bv * F;
    uint2 o;
    o.x = (unsigned int)f2b(a0[0] * 0.25f) | ((unsigned int)f2b(a0[1] * 0.25f) << 16);
    o.y = (unsigned int)f2b(a0[2] * 0.25f) | ((unsigned int)f2b(a0[3] * 0.25f) << 16);
    *(uint2*)(dst + 4 * lane) = o;
    if (lane < 8) {
        uint2 o1;
        o1.x = (unsigned int)f2b(a1[0] * 0.25f) | ((unsigned int)f2b(a1[1] * 0.25f) << 16);
        o1.y = (unsigned int)f2b(a1[2] * 0.25f) | ((unsigned int)f2b(a1[3] * 0.25f) << 16);
        *(uint2*)(dst + 256 + 4 * lane) = o1;
    }
}

// ---------------- layer-2 gather: 8 content nbrs of h1 (bf16) + style const ----------------
__global__ void agg2_kernel(const unsigned short* __restrict__ h1b,
                            const int* __restrict__ idx_k1, const int* __restrict__ idx_k2,
                            const float* __restrict__ dsc, const float* __restrict__ b1,
                            unsigned short* __restrict__ aggb) {
    int wid = threadIdx.x >> 6, lane = threadIdx.x & 63;
    int bv = blockIdx.x * 4 + wid;
    int b = bv >> 13;
    int u = 0; float w = 0.f;
    if (lane < 8)       { u = idx_k2[(size_t)bv * KNB + lane]; w = dsc[b * NT + u]; }
    else if (lane < 16) { int us = M + idx_k1[(size_t)bv * KNB + (lane - 8)]; w = dsc[b * NT + us]; }
    float S = 0.f;
    #pragma unroll
    for (int k = 8; k < 16; ++k) S += __shfl(w, k);
    float a0[4] = {0.f, 0.f, 0.f, 0.f};
    float a1[4] = {0.f, 0.f, 0.f, 0.f};
    {
        float4 bv0 = *(const float4*)(b1 + 4 * lane);
        a0[0] = fmaxf(bv0.x, 0.f) * S; a0[1] = fmaxf(bv0.y, 0.f) * S;
        a0[2] = fmaxf(bv0.z, 0.f) * S; a0[3] = fmaxf(bv0.w, 0.f) * S;
        if (lane < 8) {
            float4 bv1 = *(const float4*)(b1 + 256 + 4 * lane);
            a1[0] = fmaxf(bv1.x, 0.f) * S; a1[1] = fmaxf(bv1.y, 0.f) * S;
            a1[2] = fmaxf(bv1.z, 0.f) * S; a1[3] = fmaxf(bv1.w, 0.f) * S;
        }
    }
    const unsigned short* base = h1b + (size_t)b * M * F;
    #pragma unroll
    for (int k = 0; k < 8; ++k) {
        int   uk = __shfl(u, k);
        float wk = __shfl(w, k);
        const unsigned short* src = base + (size_t)uk * F;
        uint2 d0 = *(const uint2*)(src + 4 * lane);
        a0[0] += wk * b2f((unsigned short)(d0.x & 0xFFFF));
        a0[1] += wk * b2f((unsigned short)(d0.x >> 16));
        a0[2] += wk * b2f((unsigned short)(d0.y & 0xFFFF));
        a0[3] += wk * b2f((unsigned short)(d0.y >> 16));
        if (lane < 8) {
            uint2 d1 = *(const uint2*)(src + 256 + 4 * lane);
            a1[0] += wk * b2f((unsigned short)(d1.x & 0xFFFF));
            a1[1] += wk * b2f((unsigned short)(d1.x >> 16));
            a1[2] += wk * b2f((unsigned short)(d1.y & 0xFFFF));
            a1[3] += wk * b2f((unsigned short)(d1.y >> 16));
        }
    }
    unsigned short* dst = aggb + (size_t)bv * F;
    uint2 o;
    o.x = (unsigned int)f2b(a0[0] * 0.25f) | ((unsigned int)f2b(a0[1] * 0.25f) << 16);
    o.y = (unsigned int)f2b(a0[2] * 0.25f) | ((unsigned int)f2b(a0[3] * 0.25f) << 16);
    *(uint2*)(dst + 4 * lane) = o;
    if (lane < 8) {
        uint2 o1;
        o1.x = (unsigned int)f2b(a1[0] * 0.25f) | ((unsigned int)f2b(a1[1] * 0.25f) << 16);
        o1.y = (unsigned int)f2b(a1[2] * 0.25f) | ((unsigned int)f2b(a1[3] * 0.25f) << 16);
        *(uint2*)(dst + 256 + 4 * lane) = o1;
    }
}

// ---------------- bf16 MFMA GEMM: C[BM,288] = A(bf16) @ W + bias ----------------
// A tile: 64 rows, full K=288 staged once. B (packed Wp) staged per-32-K-step,
// double-buffered, prefetch issued before compute (drained by next barrier).
template<int RELU, int OUTBF16>
__global__ __launch_bounds__(256, 2) void gemm_kernel(
        const unsigned short* __restrict__ A,   // [BM][F] bf16
        const unsigned short* __restrict__ Wp,  // [F/8][F][8] bf16 packed
        const float* __restrict__ bias,
        void* __restrict__ Cout) {
    __shared__ __align__(16) unsigned short sA[64 * F];        // 36864 B
    __shared__ __align__(16) unsigned short sB[2][4 * F * 8];  // 2 x 18432 B
    int tid = threadIdx.x;
    int wid = tid >> 6, lane = tid & 63;
    int wm = wid & 1, wn = wid >> 1;
    int quad = lane >> 4, r16 = lane & 15;

    const unsigned short* Ab = A + (size_t)blockIdx.x * 64 * F;
    #pragma unroll
    for (int r = 0; r < 9; ++r)
        gload_lds16(Ab + (r * 256 + tid) * 8, &sA[(r * 256 + tid) * 8]);
    if (tid < 128) {
        #pragma unroll
        for (int r = 0; r < 9; ++r)
            gload_lds16(Wp + (r * 128 + tid) * 8, &sB[0][(r * 128 + tid) * 8]);
    }

    floatx4 acc[9][2];
    #pragma unroll
    for (int ct = 0; ct < 9; ++ct)
        #pragma unroll
        for (int rt = 0; rt < 2; ++rt)
            acc[ct][rt] = (floatx4){0.f, 0.f, 0.f, 0.f};

    __syncthreads();

    for (int s = 0; s < 9; ++s) {
        if (s < 8 && tid < 128) {
            const unsigned short* src = Wp + (size_t)(s + 1) * 4 * F * 8;
            unsigned short* dst = sB[(s + 1) & 1];
            #pragma unroll
            for (int r = 0; r < 9; ++r)
                gload_lds16(src + (r * 128 + tid) * 8, dst + (r * 128 + tid) * 8);
        }
        short8 a0 = *(const short8*)&sA[(wm * 32 + r16) * F + s * 32 + quad * 8];
        short8 a1 = *(const short8*)&sA[(wm * 32 + 16 + r16) * F + s * 32 + quad * 8];
        const unsigned short* bb = &sB[s & 1][(quad * F + wn * 144 + r16) * 8];
        #pragma unroll
        for (int ct = 0; ct < 9; ++ct) {
            short8 bf = *(const short8*)(bb + ct * 128);
            acc[ct][0] = __builtin_amdgcn_mfma_f32_16x16x32_bf16(a0, bf, acc[ct][0], 0, 0, 0);
            acc[ct][1] = __builtin_amdgcn_mfma_f32_16x16x32_bf16(a1, bf, acc[ct][1], 0, 0, 0);
        }
        __syncthreads();
    }

    int row0 = blockIdx.x * 64 + wm * 32 + quad * 4;
    #pragma unroll
    for (int ct = 0; ct < 9; ++ct) {
        int col = wn * 144 + ct * 16 + r16;
        float bc = bias[col];
        #pragma unroll
        for (int rt = 0; rt < 2; ++rt) {
            #pragma unroll
            for (int rg = 0; rg < 4; ++rg) {
                float v = acc[ct][rt][rg] + bc;
                if (RELU) v = fmaxf(v, 0.f);
                int row = row0 + rt * 16 + rg;
                if (OUTBF16) ((unsigned short*)Cout)[(size_t)row * F + col] = f2b(v);
                else         ((float*)Cout)[(size_t)row * F + col] = v;
            }
        }
    }
}

extern "C" void kernel_launch(void* const* d_in, const int* in_sizes, int n_in,
                              void* d_out, int out_size, void* d_ws, size_t ws_size,
                              hipStream_t stream) {
    const float* feat_c = (const float*)d_in[0];
    const float* feat_s = (const float*)d_in[1];
    const int*   idx_k1 = (const int*)d_in[2];
    const int*   idx_k2 = (const int*)d_in[3];
    const float* W1     = (const float*)d_in[4];
    const float* b1     = (const float*)d_in[5];
    const float* W2     = (const float*)d_in[6];
    const float* b2     = (const float*)d_in[7];

    // ws layout (all 256-aligned)
    char* ws = (char*)d_ws;
    float*          dsc  = (float*)ws;                               // B*NT*4   = 256 KB
    unsigned short* Wp1  = (unsigned short*)(ws + 262144);           // 165888 B
    unsigned short* Wp2  = (unsigned short*)(ws + 262144 + 165888);  // 165888 B
    unsigned short* aggb = (unsigned short*)(ws + 262144 + 2 * 165888); // BM*F*2 = 18.9 MB

    // d_out doubles as: bf16 feature table (37.75 MB) -> bf16 h1 (18.9 MB) -> final fp32
    unsigned short* featb = (unsigned short*)d_out;
    unsigned short* h1b   = (unsigned short*)d_out;
    float*          out   = (float*)d_out;

    hipMemsetAsync(dsc, 0, (size_t)B * NT * sizeof(int), stream);
    deg_kernel<<<(B * M * KNB + 255) / 256, 256, 0, stream>>>(idx_k1, idx_k2, (int*)dsc);
    rsqrt_kernel<<<(B * NT + 255) / 256, 256, 0, stream>>>(dsc);
    packw_kernel<<<(F * F + 255) / 256, 256, 0, stream>>>(W1, Wp1);
    packw_kernel<<<(F * F + 255) / 256, 256, 0, stream>>>(W2, Wp2);
    convert_kernel<<<(B * NT * F / 4 + 255) / 256, 256, 0, stream>>>(feat_c, feat_s, featb);

    agg1_kernel<<<BM / 4, 256, 0, stream>>>(featb, idx_k1, idx_k2, dsc, aggb);
    gemm_kernel<1, 1><<<BM / 64, 256, 0, stream>>>(aggb, Wp1, b1, (void*)h1b);

    agg2_kernel<<<BM / 4, 256, 0, stream>>>(h1b, idx_k1, idx_k2, dsc, b1, aggb);
    gemm_kernel<0, 0><<<BM / 64, 256, 0, stream>>>(aggb, Wp2, b2, (void*)out);
}